// Round 4
// baseline (875.082 us; speedup 1.0000x reference)
//
#include <hip/hip_runtime.h>
#include <hip/hip_bf16.h>

// 3-step Euler residual block via bf16 MFMA implicit-GEMM.
//   t = relu(conv(x,w1)+b1); x += (1/3)*(conv(t,w2)+b2); x3 times; out = relu(x)
// B=16, C=128, H=W=128. Activations NHWC bf16 in ws (XB = x state, T = t).
// Block = one (b,y) output row: 128 oc x 128 px. R6: TWO waves of 64oc x 128px
// (HK per-wave geometry, acc 4x8): 12 ds_read_b128 + 32 MFMA per K=32 step
// (reads/MFMA 0.375 vs 0.5; burst 2x). R2-R5 all pinned at MfmaUtil ~28% with
// 64x64 waves regardless of sync scheme -> geometry, not scheduling, was the
// invariant. Counted-vmcnt skeleton retained: weights 3-deep (prefetch +2),
// input slices dbuf (prefetch +1 group), vmcnt(4|8), raw s_barrier, setprio.
// Epilogue: LDS-transpose (staging LDS is dead) -> fully coalesced stores and
// residual loads (was 16x 8B scatter at 256B stride per lane).

#define BATCH 16
#define CH    128
#define HH    128
#define WW    128
#define H_STEP (1.0f/3.0f)

typedef short bf16x8 __attribute__((ext_vector_type(8)));
typedef float f32x4  __attribute__((ext_vector_type(4)));

__device__ __forceinline__ float bf2f(unsigned short u) {
    union { unsigned int i; float f; } c; c.i = ((unsigned int)u) << 16; return c.f;
}
__device__ __forceinline__ unsigned short f2bf(float f) {
    union { float f; unsigned int i; } c; c.f = f;
    unsigned int i = c.i;
    return (unsigned short)((i + 0x7FFFu + ((i >> 16) & 1u)) >> 16);  // RNE
}

// async 16B global->LDS. lptr must be wave-uniform; lane l lands at lptr+16*l.
__device__ __forceinline__ void gload16(const unsigned short* g, unsigned short* l) {
    __builtin_amdgcn_global_load_lds(
        (const __attribute__((address_space(1))) unsigned int*)g,
        (__attribute__((address_space(3))) unsigned int*)l, 16, 0, 0);
}

// ---------------- initial transpose: x0 NCHW fp32 -> XB NHWC bf16 --------------
__global__ __launch_bounds__(256)
void transpose_x(const float* __restrict__ x, unsigned short* __restrict__ xb)
{
    __shared__ unsigned short s[128 * 132];   // [ci][x], +4 pad
    const int tid = threadIdx.x;
    const int bz  = blockIdx.x;               // 0..2047 = (b,y)
    const int b = bz >> 7, y = bz & 127;

    #pragma unroll
    for (int it = 0; it < 16; ++it) {
        int idx = it * 256 + tid;             // 0..4095
        int ci = idx >> 5, xq = idx & 31;
        float4 v = *(const float4*)&x[(((size_t)b * CH + ci) * HH + y) * WW + xq * 4];
        uint2 p;
        p.x = (unsigned int)f2bf(v.x) | ((unsigned int)f2bf(v.y) << 16);
        p.y = (unsigned int)f2bf(v.z) | ((unsigned int)f2bf(v.w) << 16);
        *(uint2*)&s[ci * 132 + xq * 4] = p;
    }
    __syncthreads();
    #pragma unroll
    for (int it = 0; it < 8; ++it) {
        int idx = it * 256 + tid;             // 0..2047
        int xx = idx >> 4, cc = idx & 15;
        unsigned short t[8];
        #pragma unroll
        for (int k = 0; k < 8; ++k) t[k] = s[(cc * 8 + k) * 132 + xx];
        uint4 p;
        p.x = (unsigned int)t[0] | ((unsigned int)t[1] << 16);
        p.y = (unsigned int)t[2] | ((unsigned int)t[3] << 16);
        p.z = (unsigned int)t[4] | ((unsigned int)t[5] << 16);
        p.w = (unsigned int)t[6] | ((unsigned int)t[7] << 16);
        *(uint4*)&xb[((size_t)(b * HH + y) * WW + xx) * CH + cc * 8] = p;
    }
}

// --------------- weight convert: OIHW fp32 -> [tap][oc][ci] bf16 ---------------
__global__ __launch_bounds__(256)
void convert_w(const float* __restrict__ w, unsigned short* __restrict__ wb)
{
    int idx = blockIdx.x * 256 + threadIdx.x;   // 0..16383 = oc*128+ci
    #pragma unroll
    for (int t = 0; t < 9; ++t)
        wb[t * 16384 + idx] = f2bf(w[(size_t)idx * 9 + t]);
}

// ------------------------------ conv3x3 MFMA ----------------------------------
// MODE 0: outb = bf16(relu(acc + bias))                       (conv1 -> T)
// MODE 1: outb = bf16(res + h*(acc + bias))                   (conv2 -> XB, in place)
// MODE 2: outf = relu(res + h*(acc + bias)) fp32 NCHW         (final conv2 -> d_out)
template<int MODE>
__global__ __launch_bounds__(128, 2)
void conv_mfma(const unsigned short* __restrict__ in,   // NHWC bf16
               const unsigned short* __restrict__ wb,   // [9][128][128] bf16
               const float* __restrict__ bias,
               const unsigned short* resb,              // NHWC bf16 (may alias outb)
               unsigned short* outb,                    // NHWC bf16
               float* __restrict__ outf)                // NCHW fp32
{
    // One shared pool: staging in the loop, transpose scratch in the epilogue.
    //   s_is = smem          : 2 x [130][32] bf16 input K-slices (16640 B)
    //   s_w  = smem + 16640  : 3 x [128][32] bf16 weight tiles   (24576 B)
    // Linear LDS dests (gload_lds); bank spread via XOR-chunk swizzle on the
    // per-lane GLOBAL source addr + matching XOR on the read addr:
    //   slot (row, c) holds 16B k-chunk (c ^ (row&3)) of that row.
    __shared__ __align__(16) char smem[41216];
    unsigned short* s_is = (unsigned short*)smem;              // stride 4160/buf
    unsigned short* s_w  = (unsigned short*)(smem + 16640);    // stride 4096/buf

    const int tid = threadIdx.x;                     // 128 threads = 2 waves
    const int bz0 = blockIdx.x;
    const int bz  = ((bz0 & 7) << 8) | (bz0 >> 3);   // XCD-chunked swizzle (2048%8==0)
    const int b = bz >> 7, y = bz & 127;

    const int lane = tid & 63;
    const int wid  = tid >> 6;                       // wave = oc half
    const int n16  = lane & 15;
    const int q    = lane >> 4;

    // staging decomposition: 4 lanes per 64B row, 16 rows per gload16
    const int srow = lane >> 2;          // 0..15
    const int slot = lane & 3;           // 16B chunk slot 0..3

    const int kylo = (y == 0)      ? 1 : 0;
    const int kyhi = (y == HH - 1) ? 1 : 2;
    const int nky  = kyhi - kylo + 1;
    const int NG   = nky * 4;                        // input-slice groups
    const int NS   = NG * 3;                         // total steps

    f32x4 acc[4][8];                                 // [oc 16-blk][px 16-blk]
    #pragma unroll
    for (int i = 0; i < 4; ++i)
        #pragma unroll
        for (int j = 0; j < 8; ++j) acc[i][j] = (f32x4)0.0f;

    // stage one weight K=32 tile (128 oc x 32 ci = 8 KB), 4 gload16/wave
    auto stage_w = [&](int tap, int kq, int buf) {
        const unsigned short* wt = wb + tap * 16384 + kq * 32;
        #pragma unroll
        for (int c = 0; c < 4; ++c) {
            int row = (wid * 4 + c) * 16 + srow;             // oc 0..127
            const unsigned short* src = wt + row * 128 + ((slot ^ (row & 3)) << 3);
            gload16(src, s_w + buf * 4096 + (wid * 4 + c) * 512);
        }
    };
    // stage one input K=32 slice (rows 1..128; halos zeroed once), 4 gload16/wave
    auto stage_is = [&](int gy, int kq, int buf) {
        const size_t inrow = ((size_t)(b * HH + gy) * WW) * CH + kq * 32;
        #pragma unroll
        for (int c = 0; c < 4; ++c) {
            int r   = (wid * 4 + c) * 16 + srow;             // x 0..127
            int swz = (r + 1) & 3;                           // LDS row = x+1
            const unsigned short* src = in + inrow + (size_t)r * CH + ((slot ^ swz) << 3);
            gload16(src, s_is + buf * 4160 + ((wid * 4 + c) * 16 + 1) * 32);
        }
    };

    // ---- prologue: issue order defines the vmcnt ledger: w(0), is(0), w(1) ----
    stage_w(kylo * 3 + 0, 0, 0);                 // step 0 tile     (4 loads/wave)
    stage_is(y + kylo - 1, 0, 0);                // group 0 slice   (4 loads/wave)
    stage_w(kylo * 3 + 1, 0, 1);                 // step 1 tile     (4 loads/wave)
    // zero halo rows (x=-1, x=128) of both slice buffers, once
    if (tid < 16) {
        int bfi = tid >> 3, rr = ((tid >> 2) & 1) ? 129 : 0, cc = tid & 3;
        uint4 z = {0u, 0u, 0u, 0u};
        *(uint4*)&s_is[bfi * 4160 + rr * 32 + cc * 8] = z;
    }
    asm volatile("s_waitcnt lgkmcnt(0)" ::: "memory");   // halo writes visible

    const int NSm1 = NS - 1;
    for (int s = 0; s < NS; ++s) {
        const int g   = s / 3;
        const int kx  = s - g * 3;               // == s%3 == current wbuf index
        const int ig  = g & 1;                   // current input slice buffer

        // gate: this step's own prefetches landed; 4 (kx==0) or 8 newer loads
        // stay in flight across the barrier (never drain to 0 in the loop).
        if (kx == 0) asm volatile("s_waitcnt vmcnt(4)" ::: "memory");
        else         asm volatile("s_waitcnt vmcnt(8)" ::: "memory");
        asm volatile("s_barrier" ::: "memory");

        // prefetch weights for s+2 (tail-clamped -> redundant L2 reload keeps
        // the ledger uniform; clamped buffer is never the one being read)
        {
            int wb2 = (kx == 0) ? 2 : (kx - 1);  // (s+2)%3
            int s2  = s + 2; if (s2 > NSm1) s2 = NSm1;
            int g2  = s2 / 3, kx2 = s2 - g2 * 3;
            stage_w((kylo + (g2 >> 2)) * 3 + kx2, g2 & 3, wb2);
        }
        // prefetch next input slice at the start of each 3-step group
        if (kx == 0) {
            int gn = g + 1; if (gn > NG - 1) gn = NG - 1;
            stage_is(y + kylo + (gn >> 2) - 1, gn & 3, (g + 1) & 1);
        }

        // K=32 compute: 12 ds_read_b128 + 32 MFMA per wave
        bf16x8 af[4], bfr[8];
        #pragma unroll
        for (int i = 0; i < 4; ++i) {
            int row = wid * 64 + i * 16 + n16;
            af[i] = *(const bf16x8*)&s_w[kx * 4096 + row * 32 + ((q ^ (row & 3)) << 3)];
        }
        #pragma unroll
        for (int j = 0; j < 8; ++j) {
            int rowb = j * 16 + n16 + kx;                    // px + kx - 1, +1 halo
            bfr[j] = *(const bf16x8*)&s_is[ig * 4160 + rowb * 32 + ((q ^ (rowb & 3)) << 3)];
        }
        __builtin_amdgcn_s_setprio(1);
        #pragma unroll
        for (int i = 0; i < 4; ++i)
            #pragma unroll
            for (int j = 0; j < 8; ++j)
                acc[i][j] = __builtin_amdgcn_mfma_f32_16x16x32_bf16(
                    af[i], bfr[j], acc[i][j], 0, 0, 0);
        __builtin_amdgcn_s_setprio(0);
    }

    // ------------------------------ epilogue ---------------------------------
    const int ybase = (b * HH + y) * WW;
    if (MODE == 0) {
        // relu -> bf16 via LDS transpose: [128 px][128 oc] bf16 (32 KB), 32B-
        // granule XOR swizzle (byte ^= (px&7)<<5) to break the 256B row stride.
        asm volatile("s_waitcnt vmcnt(0) lgkmcnt(0)" ::: "memory");  // tail DMAs
        asm volatile("s_barrier" ::: "memory");
        unsigned short* sep = (unsigned short*)smem;
        #pragma unroll
        for (int j = 0; j < 8; ++j) {
            int px = j * 16 + n16;
            int sw = (px & 7) << 5;
            #pragma unroll
            for (int i = 0; i < 4; ++i) {
                int oc0 = wid * 64 + i * 16 + q * 4;
                float v0 = fmaxf(acc[i][j][0] + bias[oc0 + 0], 0.f);
                float v1 = fmaxf(acc[i][j][1] + bias[oc0 + 1], 0.f);
                float v2 = fmaxf(acc[i][j][2] + bias[oc0 + 2], 0.f);
                float v3 = fmaxf(acc[i][j][3] + bias[oc0 + 3], 0.f);
                uint2 po;
                po.x = (unsigned int)f2bf(v0) | ((unsigned int)f2bf(v1) << 16);
                po.y = (unsigned int)f2bf(v2) | ((unsigned int)f2bf(v3) << 16);
                *(uint2*)((char*)sep + ((px * 256 + oc0 * 2) ^ sw)) = po;
            }
        }
        asm volatile("s_waitcnt lgkmcnt(0)" ::: "memory");
        asm volatile("s_barrier" ::: "memory");
        #pragma unroll
        for (int it = 0; it < 16; ++it) {
            int idx = it * 128 + tid;                        // 0..2047
            int pxr = idx >> 4, cc = idx & 15;
            uint4 v = *(uint4*)((char*)sep + ((pxr * 256 + cc * 16) ^ ((pxr & 7) << 5)));
            *(uint4*)&outb[(size_t)(ybase + pxr) * CH + cc * 8] = v;
        }
    } else if (MODE == 1) {
        // res + h*(acc+bias) -> bf16. Two f32 passes (64 px x 128 oc = 32 KB)
        // through LDS; residual loads + stores fully coalesced. Arithmetic
        // order identical to the scattered version (bias added pre-LDS).
        asm volatile("s_waitcnt vmcnt(0) lgkmcnt(0)" ::: "memory");  // tail DMAs
        asm volatile("s_barrier" ::: "memory");
        float* sf = (float*)smem;
        #pragma unroll
        for (int p = 0; p < 2; ++p) {
            if (p) {
                asm volatile("s_waitcnt lgkmcnt(0)" ::: "memory");
                asm volatile("s_barrier" ::: "memory");      // pass-1 readers done
            }
            #pragma unroll
            for (int jj = 0; jj < 4; ++jj) {
                int j   = p * 4 + jj;
                int pxl = jj * 16 + n16;
                int sw  = (pxl & 7) << 5;
                #pragma unroll
                for (int i = 0; i < 4; ++i) {
                    int oc0 = wid * 64 + i * 16 + q * 4;
                    f32x4 w = acc[i][j];
                    w[0] += bias[oc0 + 0]; w[1] += bias[oc0 + 1];
                    w[2] += bias[oc0 + 2]; w[3] += bias[oc0 + 3];
                    *(f32x4*)((char*)sf + ((pxl * 512 + oc0 * 4) ^ sw)) = w;
                }
            }
            asm volatile("s_waitcnt lgkmcnt(0)" ::: "memory");
            asm volatile("s_barrier" ::: "memory");
            #pragma unroll
            for (int it = 0; it < 16; ++it) {
                int idx = it * 128 + tid;                    // 0..2047
                int pxl = idx >> 5, c4 = idx & 31;           // px-local, 4-oc chunk
                f32x4 v = *(f32x4*)((char*)sf +
                            ((pxl * 512 + c4 * 16) ^ ((pxl & 7) << 5)));
                size_t gb = (size_t)(ybase + p * 64 + pxl) * CH + c4 * 4;
                uint2 rr = *(const uint2*)&resb[gb];
                float o0 = bf2f((unsigned short)(rr.x & 0xffff)) + H_STEP * v[0];
                float o1 = bf2f((unsigned short)(rr.x >> 16))    + H_STEP * v[1];
                float o2 = bf2f((unsigned short)(rr.y & 0xffff)) + H_STEP * v[2];
                float o3 = bf2f((unsigned short)(rr.y >> 16))    + H_STEP * v[3];
                uint2 po;
                po.x = (unsigned int)f2bf(o0) | ((unsigned int)f2bf(o1) << 16);
                po.y = (unsigned int)f2bf(o2) | ((unsigned int)f2bf(o3) << 16);
                *(uint2*)&outb[gb] = po;
            }
        }
    } else {
        // fp32 NCHW out + final relu (stores already coalesced along x);
        // residual still bf16 NHWC (scattered reads; 1 of 6 dispatches).
        #pragma unroll
        for (int i = 0; i < 4; ++i) {
            #pragma unroll
            for (int r = 0; r < 4; ++r) {
                int oc = wid * 64 + i * 16 + q * 4 + r;
                float bv = bias[oc];
                size_t orow = ((size_t)(b * CH + oc) * HH + y) * WW;
                #pragma unroll
                for (int j = 0; j < 8; ++j) {
                    int x = j * 16 + n16;
                    float v = acc[i][j][r] + bv;
                    v = bf2f(resb[(size_t)(ybase + x) * CH + oc]) + H_STEP * v;
                    outf[orow + x] = fmaxf(v, 0.f);
                }
            }
        }
    }
}

// ------------------------------------------------------------------------------
extern "C" void kernel_launch(void* const* d_in, const int* in_sizes, int n_in,
                              void* d_out, int out_size, void* d_ws, size_t ws_size,
                              hipStream_t stream) {
    const float* x0 = (const float*)d_in[0];
    const float* w1 = (const float*)d_in[1];
    const float* b1 = (const float*)d_in[2];
    const float* w2 = (const float*)d_in[3];
    const float* b2 = (const float*)d_in[4];

    const size_t NELEM = (size_t)BATCH * CH * HH * WW;       // 33,554,432
    unsigned short* XB = (unsigned short*)d_ws;              // x state, NHWC bf16
    unsigned short* T  = XB + NELEM;                         // t,       NHWC bf16

    unsigned short* WB1;
    if (ws_size >= NELEM * 4 + 2 * 294912)
        WB1 = T + NELEM;
    else
        WB1 = (unsigned short*)d_in[0];                      // x0 dead after transpose
    unsigned short* WB2 = WB1 + 9 * 16384;

    dim3 block(256);
    dim3 block2(128);
    dim3 gridRow(BATCH * HH);    // 2048: one block per (b, y)

    transpose_x<<<gridRow, block, 0, stream>>>(x0, XB);      // reads x0 first
    convert_w<<<dim3(64), block, 0, stream>>>(w1, WB1);      // then x0 may be clobbered
    convert_w<<<dim3(64), block, 0, stream>>>(w2, WB2);

    // step 1
    conv_mfma<0><<<gridRow, block2, 0, stream>>>(XB, WB1, b1, nullptr, T, nullptr);
    conv_mfma<1><<<gridRow, block2, 0, stream>>>(T, WB2, b2, XB, XB, nullptr);
    // step 2
    conv_mfma<0><<<gridRow, block2, 0, stream>>>(XB, WB1, b1, nullptr, T, nullptr);
    conv_mfma<1><<<gridRow, block2, 0, stream>>>(T, WB2, b2, XB, XB, nullptr);
    // step 3 (final relu, fp32 NCHW out)
    conv_mfma<0><<<gridRow, block2, 0, stream>>>(XB, WB1, b1, nullptr, T, nullptr);
    conv_mfma<2><<<gridRow, block2, 0, stream>>>(T, WB2, b2, XB, nullptr, (float*)d_out);
}

// Round 5
// 717.102 us; speedup vs baseline: 1.2203x; 1.2203x over previous
//
#include <hip/hip_runtime.h>
#include <hip/hip_bf16.h>

// 3-step Euler residual block via bf16 MFMA implicit-GEMM.
//   t = relu(conv(x,w1)+b1); x += (1/3)*(conv(t,w2)+b2); x3 times; out = relu(x)
// B=16, C=128, H=W=128. Activations NHWC bf16 in ws (XB = x state, T = t).
//
// R7: two-row blocks. Block = out rows (y, y+64) of one image: 128 oc x 256 px,
// 4 waves = (oc-half, window), each 64oc x 128px (acc 4x8). Fixes R6's
// occupancy collapse (6 waves/CU) while keeping its geometry: 8 waves/CU,
// reads/MFMA 0.375, weight staging + barriers halved per FLOP. Uniform 36-step
// schedule for ALL blocks: boundary (ky,window) combos read a zeroed LDS slice
// (DMA still issued from a clamped row -> vmcnt ledger stays uniform).
// Counted-vmcnt skeleton (R5): weights 3-deep prefetch +2, input slices dbuf'd
// per window prefetch +1 group, gates vmcnt(2|6), raw s_barrier, setprio.
// Staging swizzle f(R)=(R>>1)&3 on 16B chunks (write source + read) -> 2-way.

#define BATCH 16
#define CH    128
#define HH    128
#define WW    128
#define H_STEP (1.0f/3.0f)

typedef short bf16x8 __attribute__((ext_vector_type(8)));
typedef float f32x4  __attribute__((ext_vector_type(4)));

__device__ __forceinline__ float bf2f(unsigned short u) {
    union { unsigned int i; float f; } c; c.i = ((unsigned int)u) << 16; return c.f;
}
__device__ __forceinline__ unsigned short f2bf(float f) {
    union { float f; unsigned int i; } c; c.f = f;
    unsigned int i = c.i;
    return (unsigned short)((i + 0x7FFFu + ((i >> 16) & 1u)) >> 16);  // RNE
}

// async 16B global->LDS. lptr must be wave-uniform; lane l lands at lptr+16*l.
__device__ __forceinline__ void gload16(const unsigned short* g, unsigned short* l) {
    __builtin_amdgcn_global_load_lds(
        (const __attribute__((address_space(1))) unsigned int*)g,
        (__attribute__((address_space(3))) unsigned int*)l, 16, 0, 0);
}

// ---------------- initial transpose: x0 NCHW fp32 -> XB NHWC bf16 --------------
__global__ __launch_bounds__(256)
void transpose_x(const float* __restrict__ x, unsigned short* __restrict__ xb)
{
    __shared__ unsigned short s[128 * 132];   // [ci][x], +4 pad
    const int tid = threadIdx.x;
    const int bz  = blockIdx.x;               // 0..2047 = (b,y)
    const int b = bz >> 7, y = bz & 127;

    #pragma unroll
    for (int it = 0; it < 16; ++it) {
        int idx = it * 256 + tid;             // 0..4095
        int ci = idx >> 5, xq = idx & 31;
        float4 v = *(const float4*)&x[(((size_t)b * CH + ci) * HH + y) * WW + xq * 4];
        uint2 p;
        p.x = (unsigned int)f2bf(v.x) | ((unsigned int)f2bf(v.y) << 16);
        p.y = (unsigned int)f2bf(v.z) | ((unsigned int)f2bf(v.w) << 16);
        *(uint2*)&s[ci * 132 + xq * 4] = p;
    }
    __syncthreads();
    #pragma unroll
    for (int it = 0; it < 8; ++it) {
        int idx = it * 256 + tid;             // 0..2047
        int xx = idx >> 4, cc = idx & 15;
        unsigned short t[8];
        #pragma unroll
        for (int k = 0; k < 8; ++k) t[k] = s[(cc * 8 + k) * 132 + xx];
        uint4 p;
        p.x = (unsigned int)t[0] | ((unsigned int)t[1] << 16);
        p.y = (unsigned int)t[2] | ((unsigned int)t[3] << 16);
        p.z = (unsigned int)t[4] | ((unsigned int)t[5] << 16);
        p.w = (unsigned int)t[6] | ((unsigned int)t[7] << 16);
        *(uint4*)&xb[((size_t)(b * HH + y) * WW + xx) * CH + cc * 8] = p;
    }
}

// --------------- weight convert: OIHW fp32 -> [tap][oc][ci] bf16 ---------------
__global__ __launch_bounds__(256)
void convert_w(const float* __restrict__ w, unsigned short* __restrict__ wb)
{
    int idx = blockIdx.x * 256 + threadIdx.x;   // 0..16383 = oc*128+ci
    #pragma unroll
    for (int t = 0; t < 9; ++t)
        wb[t * 16384 + idx] = f2bf(w[(size_t)idx * 9 + t]);
}

// ------------------------------ conv3x3 MFMA ----------------------------------
// MODE 0: outb = bf16(relu(acc + bias))                       (conv1 -> T)
// MODE 1: outb = bf16(res + h*(acc + bias))                   (conv2 -> XB, in place)
// MODE 2: outf = relu(res + h*(acc + bias)) fp32 NCHW         (final conv2 -> d_out)
template<int MODE>
__global__ __launch_bounds__(256, 2)
void conv_mfma(const unsigned short* __restrict__ in,   // NHWC bf16
               const unsigned short* __restrict__ wb,   // [9][128][128] bf16
               const float* __restrict__ bias,
               const unsigned short* resb,              // NHWC bf16 (may alias outb)
               unsigned short* outb,                    // NHWC bf16
               float* __restrict__ outf)                // NCHW fp32
{
    // LDS pool (66176 B), shorts offsets:
    //   s_is   @     0 : 4 input K=32 slices [130][32], slice = win*2+buf, 4x8320 B
    //   s_zero @ 16640 : one permanently-zero slice (boundary ky redirect), 8320 B
    //   s_w    @ 20800 : 3 weight K=32 tiles [128][32], 3x8192 B
    // Epilogue reuses the pool as transpose scratch (64 KB).
    // Chunk swizzle both-sides: LDS slot (R, c) holds global chunk c ^ ((R>>1)&3).
    __shared__ __align__(16) char smem[66176];
    unsigned short* s_is   = (unsigned short*)smem;
    unsigned short* s_zero = (unsigned short*)smem + 16640;
    unsigned short* s_w    = (unsigned short*)smem + 20800;

    const int tid = threadIdx.x;                     // 256 threads = 4 waves
    const int bz0 = blockIdx.x;
    const int bz  = ((bz0 & 7) << 7) | (bz0 >> 3);   // XCD swizzle (1024 = 8*128)
    const int b  = bz >> 6, yp = bz & 63;
    const int yA = yp, yB = yp + 64;

    const int lane = tid & 63;
    const int wid  = tid >> 6;
    const int win  = wid & 1;                        // window: 0 -> yA, 1 -> yB
    const int och  = (wid >> 1) * 64;                // oc half
    const int yw   = win ? yB : yA;                  // this wave's out row
    const int n16  = lane & 15;
    const int q    = lane >> 4;

    // staging decomposition: 4 lanes per 64B row, 16 rows per gload16
    const int srow = lane >> 2;          // 0..15
    const int slot = lane & 3;           // 16B chunk slot 0..3

    f32x4 acc[4][8];                                 // [oc 16-blk][px 16-blk]
    #pragma unroll
    for (int i = 0; i < 4; ++i)
        #pragma unroll
        for (int j = 0; j < 8; ++j) acc[i][j] = (f32x4)0.0f;

    // stage one weight K=32 tile (128 oc x 32 ci = 8 KB), 2 gload16/wave
    auto stage_w = [&](int tap, int kq, int buf) {
        const unsigned short* wt = wb + tap * 16384 + kq * 32;
        #pragma unroll
        for (int c = 0; c < 2; ++c) {
            int row = (wid * 2 + c) * 16 + srow;             // oc 0..127
            const unsigned short* src = wt + row * 128 + ((slot ^ ((row >> 1) & 3)) << 3);
            gload16(src, s_w + buf * 4096 + (wid * 2 + c) * 512);
        }
    };
    // stage one input K=32 slice into slice sl (rows 1..128), 2 gload16/wave.
    // gy clamped: boundary combos stage garbage that is never read (zero-slice
    // redirect) -- the DMA is still issued so the vmcnt ledger stays uniform.
    auto stage_is = [&](int gy, int kq, int sl) {
        gy = gy < 0 ? 0 : (gy > HH - 1 ? HH - 1 : gy);
        const size_t inrow = ((size_t)(b * HH + gy) * WW) * CH + kq * 32;
        #pragma unroll
        for (int c = 0; c < 2; ++c) {
            int r = (wid * 2 + c) * 16 + srow;               // x 0..127
            const unsigned short* src =
                in + inrow + (size_t)r * CH + ((slot ^ (((r + 1) >> 1) & 3)) << 3);
            gload16(src, s_is + sl * 4160 + ((wid * 2 + c) * 16 + 1) * 32);
        }
    };

    // ---- prologue. Ledger issue order: w(s0)[2], isA(g0)[2], isB(g0)[2], w(s1)[2]
    stage_w(0, 0, 0);                    // s=0: ky0,kx0
    stage_is(yA - 1, 0, 0);              // window A, group 0, buf 0
    stage_is(yB - 1, 0, 2);              // window B, group 0, buf 0
    stage_w(1, 0, 1);                    // s=1: ky0,kx1
    // zero-fill: the zero slice (520 x 16B) + halo rows 0/129 of 4 slices
    #pragma unroll
    for (int it = 0; it < 3; ++it) {
        int idx = it * 256 + tid;
        if (idx < 520) {
            uint4 z = {0u, 0u, 0u, 0u};
            *(uint4*)&s_zero[idx * 8] = z;
        }
    }
    if (tid < 32) {
        int sl = tid >> 3, hr = ((tid >> 2) & 1) ? 129 : 0, cc = tid & 3;
        uint4 z = {0u, 0u, 0u, 0u};
        *(uint4*)&s_is[sl * 4160 + hr * 32 + cc * 8] = z;
    }
    asm volatile("s_waitcnt lgkmcnt(0)" ::: "memory");   // LDS zero-writes done

    int kx = 0, g = 0;                   // s = g*3 + kx; wbuf(s) == kx
    for (int s = 0; s < 36; ++s) {
        const int ky = g >> 2;
        const int ib = g & 1;            // current input buf

        // gate: this step's own prefetches landed; newer loads (2 or 6) stay
        // in flight across the barrier (never drained to 0 in the loop).
        if (kx == 0) asm volatile("s_waitcnt vmcnt(2)" ::: "memory");
        else         asm volatile("s_waitcnt vmcnt(6)" ::: "memory");
        asm volatile("s_barrier" ::: "memory");

        // prefetch weights for s+2 (tail-clamped; clamped buf never read after)
        {
            int g2 = g, kx2 = kx + 2;
            if (kx2 >= 3) { kx2 -= 3; ++g2; }
            if (g2 > 11)  { g2 = 11; kx2 = 2; }
            int wb2 = (kx == 0) ? 2 : (kx - 1);      // (s+2)%3
            stage_w((g2 >> 2) * 3 + kx2, g2 & 3, wb2);
        }
        // prefetch both windows' next input slice at each group start
        if (kx == 0) {
            int gn = g + 1; if (gn > 11) gn = 11;
            int kyn = gn >> 2, kqn = gn & 3, bn = gn & 1;
            stage_is(yA + kyn - 1, kqn, bn);
            stage_is(yB + kyn - 1, kqn, 2 + bn);
        }

        // input base for this wave: boundary (ky,window) reads the zero slice
        const int gyw = yw + ky - 1;
        const unsigned short* ibase =
            (gyw >= 0 && gyw < HH) ? (s_is + (win * 2 + ib) * 4160) : s_zero;

        // K=32 compute: 12 ds_read_b128 + 32 MFMA per wave
        bf16x8 af[4], bfr[8];
        #pragma unroll
        for (int i = 0; i < 4; ++i) {
            int row = och + i * 16 + n16;
            af[i] = *(const bf16x8*)&s_w[kx * 4096 + row * 32 +
                                         ((q ^ ((row >> 1) & 3)) << 3)];
        }
        #pragma unroll
        for (int j = 0; j < 8; ++j) {
            int rowb = j * 16 + n16 + kx;            // px + kx - 1, +1 halo
            bfr[j] = *(const bf16x8*)&ibase[rowb * 32 +
                                           ((q ^ ((rowb >> 1) & 3)) << 3)];
        }
        __builtin_amdgcn_s_setprio(1);
        #pragma unroll
        for (int i = 0; i < 4; ++i)
            #pragma unroll
            for (int j = 0; j < 8; ++j)
                acc[i][j] = __builtin_amdgcn_mfma_f32_16x16x32_bf16(
                    af[i], bfr[j], acc[i][j], 0, 0, 0);
        __builtin_amdgcn_s_setprio(0);

        if (++kx == 3) { kx = 0; ++g; }
    }

    // ------------------------------ epilogue ---------------------------------
    asm volatile("s_waitcnt vmcnt(0) lgkmcnt(0)" ::: "memory");  // tail DMAs
    asm volatile("s_barrier" ::: "memory");
    const size_t ybw = (size_t)(b * HH + yw) * WW;   // this wave's out-row base

    if (MODE == 0) {
        // relu -> bf16 via LDS transpose: [2 win][128 px][128 oc] bf16 (64 KB),
        // 32B-granule XOR swizzle (byte ^= (px&7)<<5) breaks the 256B stride.
        unsigned short* sep = (unsigned short*)smem;
        #pragma unroll
        for (int j = 0; j < 8; ++j) {
            int px = j * 16 + n16;
            int sw = (px & 7) << 5;
            #pragma unroll
            for (int i = 0; i < 4; ++i) {
                int oc0 = och + i * 16 + q * 4;
                float v0 = fmaxf(acc[i][j][0] + bias[oc0 + 0], 0.f);
                float v1 = fmaxf(acc[i][j][1] + bias[oc0 + 1], 0.f);
                float v2 = fmaxf(acc[i][j][2] + bias[oc0 + 2], 0.f);
                float v3 = fmaxf(acc[i][j][3] + bias[oc0 + 3], 0.f);
                uint2 po;
                po.x = (unsigned int)f2bf(v0) | ((unsigned int)f2bf(v1) << 16);
                po.y = (unsigned int)f2bf(v2) | ((unsigned int)f2bf(v3) << 16);
                *(uint2*)((char*)sep + win * 32768 + ((px * 256 + oc0 * 2) ^ sw)) = po;
            }
        }
        asm volatile("s_waitcnt lgkmcnt(0)" ::: "memory");
        asm volatile("s_barrier" ::: "memory");
        #pragma unroll
        for (int it = 0; it < 16; ++it) {
            int idx = it * 256 + tid;                        // 0..4095
            int w2 = idx >> 11, pxr = (idx >> 4) & 127, cc = idx & 15;
            uint4 v = *(uint4*)((char*)smem + w2 * 32768 +
                                ((pxr * 256 + cc * 16) ^ ((pxr & 7) << 5)));
            int y2 = w2 ? yB : yA;
            *(uint4*)&outb[((size_t)(b * HH + y2) * WW + pxr) * CH + cc * 8] = v;
        }
    } else if (MODE == 1) {
        // res + h*(acc+bias) -> bf16, two f32 passes (2 win x 64 px x 128 oc =
        // 64 KB each); residual loads + stores fully coalesced.
        float* sf = (float*)smem;
        #pragma unroll
        for (int p = 0; p < 2; ++p) {
            if (p) asm volatile("s_barrier" ::: "memory");   // pass-0 readers done
            #pragma unroll
            for (int jj = 0; jj < 4; ++jj) {
                int j   = p * 4 + jj;
                int pxl = jj * 16 + n16;
                int sw  = (pxl & 7) << 5;
                #pragma unroll
                for (int i = 0; i < 4; ++i) {
                    int oc0 = och + i * 16 + q * 4;
                    f32x4 w = acc[i][j];
                    w[0] += bias[oc0 + 0]; w[1] += bias[oc0 + 1];
                    w[2] += bias[oc0 + 2]; w[3] += bias[oc0 + 3];
                    *(f32x4*)((char*)sf + win * 32768 + ((pxl * 512 + oc0 * 4) ^ sw)) = w;
                }
            }
            asm volatile("s_waitcnt lgkmcnt(0)" ::: "memory");
            asm volatile("s_barrier" ::: "memory");
            #pragma unroll
            for (int it = 0; it < 16; ++it) {
                int idx = it * 256 + tid;                    // 0..4095
                int w2 = idx >> 11, pxl = (idx >> 5) & 63, c4 = idx & 31;
                f32x4 v = *(f32x4*)((char*)sf + w2 * 32768 +
                                    ((pxl * 512 + c4 * 16) ^ ((pxl & 7) << 5)));
                int y2 = w2 ? yB : yA;
                size_t gb = ((size_t)(b * HH + y2) * WW + p * 64 + pxl) * CH + c4 * 4;
                uint2 rr = *(const uint2*)&resb[gb];
                float o0 = bf2f((unsigned short)(rr.x & 0xffff)) + H_STEP * v[0];
                float o1 = bf2f((unsigned short)(rr.x >> 16))    + H_STEP * v[1];
                float o2 = bf2f((unsigned short)(rr.y & 0xffff)) + H_STEP * v[2];
                float o3 = bf2f((unsigned short)(rr.y >> 16))    + H_STEP * v[3];
                uint2 po;
                po.x = (unsigned int)f2bf(o0) | ((unsigned int)f2bf(o1) << 16);
                po.y = (unsigned int)f2bf(o2) | ((unsigned int)f2bf(o3) << 16);
                *(uint2*)&outb[gb] = po;
            }
        }
    } else {
        // fp32 NCHW out + final relu (stores coalesced along x); residual bf16
        // NHWC (scattered reads; 2 of 6 dispatches... only the final one).
        #pragma unroll
        for (int i = 0; i < 4; ++i) {
            #pragma unroll
            for (int r = 0; r < 4; ++r) {
                int oc = och + i * 16 + q * 4 + r;
                float bv = bias[oc];
                size_t orow = ((size_t)(b * CH + oc) * HH + yw) * WW;
                #pragma unroll
                for (int j = 0; j < 8; ++j) {
                    int x = j * 16 + n16;
                    float v = acc[i][j][r] + bv;
                    v = bf2f(resb[(ybw + x) * CH + oc]) + H_STEP * v;
                    outf[orow + x] = fmaxf(v, 0.f);
                }
            }
        }
    }
}

// ------------------------------------------------------------------------------
extern "C" void kernel_launch(void* const* d_in, const int* in_sizes, int n_in,
                              void* d_out, int out_size, void* d_ws, size_t ws_size,
                              hipStream_t stream) {
    const float* x0 = (const float*)d_in[0];
    const float* w1 = (const float*)d_in[1];
    const float* b1 = (const float*)d_in[2];
    const float* w2 = (const float*)d_in[3];
    const float* b2 = (const float*)d_in[4];

    const size_t NELEM = (size_t)BATCH * CH * HH * WW;       // 33,554,432
    unsigned short* XB = (unsigned short*)d_ws;              // x state, NHWC bf16
    unsigned short* T  = XB + NELEM;                         // t,       NHWC bf16

    unsigned short* WB1;
    if (ws_size >= NELEM * 4 + 2 * 294912)
        WB1 = T + NELEM;
    else
        WB1 = (unsigned short*)d_in[0];                      // x0 dead after transpose
    unsigned short* WB2 = WB1 + 9 * 16384;

    dim3 block(256);
    dim3 gridRow(BATCH * HH);     // 2048: transpose, one block per (b, y)
    dim3 gridConv(BATCH * 64);    // 1024: conv, one block per (b, y-pair)

    transpose_x<<<gridRow, block, 0, stream>>>(x0, XB);      // reads x0 first
    convert_w<<<dim3(64), block, 0, stream>>>(w1, WB1);      // then x0 may be clobbered
    convert_w<<<dim3(64), block, 0, stream>>>(w2, WB2);

    // step 1
    conv_mfma<0><<<gridConv, block, 0, stream>>>(XB, WB1, b1, nullptr, T, nullptr);
    conv_mfma<1><<<gridConv, block, 0, stream>>>(T, WB2, b2, XB, XB, nullptr);
    // step 2
    conv_mfma<0><<<gridConv, block, 0, stream>>>(XB, WB1, b1, nullptr, T, nullptr);
    conv_mfma<1><<<gridConv, block, 0, stream>>>(T, WB2, b2, XB, XB, nullptr);
    // step 3 (final relu, fp32 NCHW out)
    conv_mfma<0><<<gridConv, block, 0, stream>>>(XB, WB1, b1, nullptr, T, nullptr);
    conv_mfma<2><<<gridConv, block, 0, stream>>>(T, WB2, b2, XB, nullptr, (float*)d_out);
}